// Round 4
// baseline (1291.253 us; speedup 1.0000x reference)
//
#include <hip/hip_runtime.h>

#define B_ 4
#define S_ 2048
#define HID_ 2048
#define NH_ 16
#define NKV_ 4
#define HD_ 128
#define NTOK (B_ * S_)                 // 8192
#define QKV_N 3072                     // (NH + 2*NKV) * HD
#define KV_N 1024                      // 2*NKV*HD (K at col 0, V at col 512)
#define SCALE_ 0.08838834764831845f    // 128^-0.5
#define NEG_ -30000.0f

typedef __attribute__((ext_vector_type(8))) short short8;
typedef __attribute__((ext_vector_type(4))) float f32x4;
typedef unsigned short ushort_t;
typedef unsigned int uint32;

__device__ __forceinline__ float sanit(float x) {
    if (!(x == x)) x = 0.0f;
    return fminf(fmaxf(x, -65504.0f), 65504.0f);
}
__device__ __forceinline__ ushort_t f2bf(float f) {
    union { float f; uint32 u; } c; c.f = f;
    uint32 u = c.u;
    u += 0x7fffu + ((u >> 16) & 1u);          // round-to-nearest-even
    return (ushort_t)(u >> 16);
}
__device__ __forceinline__ ushort_t f2bf_s(float f) { return f2bf(sanit(f)); }
__device__ __forceinline__ float bf2f(ushort_t h) {
    union { float f; uint32 u; } c; c.u = ((uint32)h) << 16;
    return c.f;
}

// ---------------------------------------------------------------------------
// GEMM: C = A[M,K] @ B[K,N]. B is always fp32 (weights). A is fp32 (AF32=1)
// or bf16 (AF32=0). Internal compute bf16 MFMA, fp32 acc.
// SPLIT=1: bf16 epilogue, cols < 2048 -> C0 (ld 2048), cols >= 2048 -> C1
//          (ld 1024).  SPLIT=0: fp32 epilogue into C0 (ld N).
// 128x128 tile, 4 waves of 64x64 (4x4 of 16x16x32 MFMA), BK=32.
// ---------------------------------------------------------------------------
template <int SPLIT, int AF32>
__global__ __launch_bounds__(256, 2) void gemm_k(
    const void* __restrict__ Ap, const float* __restrict__ Bm,
    void* __restrict__ C0, ushort_t* __restrict__ C1,
    int M, int N, int K) {
    __shared__ __align__(16) ushort_t As[128][40];
    __shared__ __align__(16) ushort_t Bs[128][40]; // transposed: Bs[n][k]

    const int tid  = threadIdx.x;
    const int lane = tid & 63;
    const int w    = tid >> 6;
    const int wm   = (w >> 1) * 64;
    const int wn   = (w & 1) * 64;
    const int m0   = blockIdx.y * 128;
    const int n0   = blockIdx.x * 128;
    const int col  = lane & 15;
    const int quad = lane >> 4;

    f32x4 acc[4][4] = {};

    const int ar = tid >> 1;          // A stage row 0..127
    const int ak = (tid & 1) * 16;    // A stage k-offset {0,16}
    const int br = tid >> 3;          // B stage k-row 0..31
    const int bn = (tid & 7) * 16;    // B stage n-offset {0..112}

    for (int k0 = 0; k0 < K; k0 += 32) {
        __syncthreads();
        {
            // ---- A tile -> bf16 LDS ----
            ushort_t ua[16];
            if (AF32) {
                const float* ag = (const float*)Ap + (size_t)(m0 + ar) * K + k0 + ak;
                union { float4 v; float f[4]; } t;
#pragma unroll
                for (int q = 0; q < 4; ++q) {
                    t.v = *(const float4*)(ag + q * 4);
#pragma unroll
                    for (int e = 0; e < 4; ++e) ua[q * 4 + e] = f2bf(t.f[e]);
                }
            } else {
                const ushort_t* ag = (const ushort_t*)Ap + (size_t)(m0 + ar) * K + k0 + ak;
                union { float4 v; ushort_t u[8]; } t0, t1;
                t0.v = *(const float4*)ag;
                t1.v = *(const float4*)(ag + 8);
#pragma unroll
                for (int e = 0; e < 8; ++e) { ua[e] = t0.u[e]; ua[8 + e] = t1.u[e]; }
            }
            *(short8*)&As[ar][ak]     = *(short8*)&ua[0];
            *(short8*)&As[ar][ak + 8] = *(short8*)&ua[8];

            // ---- B tile (fp32) -> transposed bf16 LDS ----
            const float* bg = Bm + (size_t)(k0 + br) * N + n0 + bn;
            union { float4 v; float f[4]; } tb;
#pragma unroll
            for (int q = 0; q < 4; ++q) {
                tb.v = *(const float4*)(bg + q * 4);
#pragma unroll
                for (int e = 0; e < 4; ++e) Bs[bn + q * 4 + e][br] = f2bf(tb.f[e]);
            }
        }
        __syncthreads();

        short8 af[4], bfr[4];
#pragma unroll
        for (int mt = 0; mt < 4; ++mt)
            af[mt] = *(const short8*)&As[wm + mt * 16 + col][quad * 8];
#pragma unroll
        for (int nt = 0; nt < 4; ++nt)
            bfr[nt] = *(const short8*)&Bs[wn + nt * 16 + col][quad * 8];
#pragma unroll
        for (int mt = 0; mt < 4; ++mt)
#pragma unroll
            for (int nt = 0; nt < 4; ++nt)
                acc[mt][nt] = __builtin_amdgcn_mfma_f32_16x16x32_bf16(
                    af[mt], bfr[nt], acc[mt][nt], 0, 0, 0);
    }

    if (SPLIT) {
        ushort_t* dst;
        int ldc, coff;
        if (n0 >= 2048) { dst = C1; ldc = KV_N; coff = 2048; }
        else            { dst = (ushort_t*)C0; ldc = HID_; coff = 0; }
#pragma unroll
        for (int mt = 0; mt < 4; ++mt)
#pragma unroll
            for (int nt = 0; nt < 4; ++nt)
#pragma unroll
                for (int r = 0; r < 4; ++r) {
                    int row = m0 + wm + mt * 16 + quad * 4 + r;
                    int cc  = n0 + wn + nt * 16 + col - coff;
                    dst[(size_t)row * ldc + cc] = f2bf_s(acc[mt][nt][r]);
                }
    } else {
        float* dst = (float*)C0;
#pragma unroll
        for (int mt = 0; mt < 4; ++mt)
#pragma unroll
            for (int nt = 0; nt < 4; ++nt)
#pragma unroll
                for (int r = 0; r < 4; ++r) {
                    int row = m0 + wm + mt * 16 + quad * 4 + r;
                    int cc  = n0 + wn + nt * 16 + col;
                    dst[(size_t)row * N + cc] = sanit(acc[mt][nt][r]);
                }
    }
}

// ---------------------------------------------------------------------------
// RoPE in-place on bf16 buffers. Q in qbuf [8192][2048] (heads 0..15); K in
// kvbuf [8192][1024] cols 0..511. One thread per (tok, head, d<64).
// ---------------------------------------------------------------------------
__global__ void rope_kernel(ushort_t* __restrict__ qbuf,
                            ushort_t* __restrict__ kvbuf) {
    int p = blockIdx.x * blockDim.x + threadIdx.x;
    const int total = NTOK * 20 * 64;
    if (p >= total) return;
    int d    = p & 63;
    int rest = p >> 6;
    int head = rest % 20;            // 0..15 Q, 16..19 K
    int tok  = rest / 20;
    int s    = tok & (S_ - 1);

    ushort_t* base;
    if (head < 16) base = qbuf  + (size_t)tok * HID_ + head * HD_ + d;
    else           base = kvbuf + (size_t)tok * KV_N + (head - 16) * HD_ + d;

    float x1 = bf2f(base[0]);
    float x2 = bf2f(base[64]);

    float inv_freq = powf(10000.0f, -(float)d * (1.0f / 64.0f));
    float ang = (float)s * inv_freq;
    float sn, cs;
    sincosf(ang, &sn, &cs);

    base[0]  = f2bf_s(x1 * cs - x2 * sn);
    base[64] = f2bf_s(x2 * cs + x1 * sn);
}

// ---------------------------------------------------------------------------
// Flash attention, causal, GQA (kv head = q head >> 2). All bf16 buffers.
// 4 waves, BQ=64 (16 Q rows per wave), BK=64.
// ---------------------------------------------------------------------------
__global__ __launch_bounds__(256, 2) void flash_kernel(
    const ushort_t* __restrict__ qbuf, const ushort_t* __restrict__ kvbuf,
    ushort_t* __restrict__ obuf) {
    __shared__ __align__(16) ushort_t Ks[64][136];
    __shared__ __align__(16) ushort_t Vs[64][136];
    __shared__ __align__(16) ushort_t Ps[4][16][72];

    const int tid  = threadIdx.x;
    const int lane = tid & 63;
    const int w    = tid >> 6;
    const int col  = lane & 15;
    const int quad = lane >> 4;
    const int q0   = blockIdx.x * 64;
    const int h    = blockIdx.y;
    const int b    = blockIdx.z;
    const int kvh  = h >> 2;
    const int bS   = b * S_;

    short8 qf[4];
    {
        const ushort_t* qp = qbuf + (size_t)(bS + q0 + w * 16 + col) * HID_
                             + h * HD_ + quad * 8;
#pragma unroll
        for (int kt = 0; kt < 4; ++kt) qf[kt] = *(const short8*)(qp + kt * 32);
    }

    float m_i[4], l_i[4];
#pragma unroll
    for (int r = 0; r < 4; ++r) { m_i[r] = NEG_; l_i[r] = 0.f; }
    f32x4 o[8] = {};

    const int i_row  = q0 + w * 16 + quad * 4;   // + r
    const int ntiles = q0 / 64 + 1;

    const int jr   = tid >> 2;        // stage row 0..63
    const int doff = (tid & 3) * 32;  // stage d-offset

    for (int t = 0; t < ntiles; ++t) {
        const int j0 = t * 64;
        __syncthreads();
        {
            const ushort_t* kg = kvbuf + (size_t)(bS + j0 + jr) * KV_N
                                 + kvh * HD_ + doff;
#pragma unroll
            for (int i = 0; i < 4; ++i) {
                *(float4*)&Ks[jr][doff + i * 8] = *(const float4*)(kg + i * 8);
                *(float4*)&Vs[jr][doff + i * 8] = *(const float4*)(kg + 512 + i * 8);
            }
        }
        __syncthreads();

        // S = Q K^T
        f32x4 s[4] = {};
#pragma unroll
        for (int ct = 0; ct < 4; ++ct)
#pragma unroll
            for (int kt = 0; kt < 4; ++kt) {
                short8 kf = *(const short8*)&Ks[ct * 16 + col][kt * 32 + quad * 8];
                s[ct] = __builtin_amdgcn_mfma_f32_16x16x32_bf16(qf[kt], kf, s[ct], 0, 0, 0);
            }

        // scale + causal mask
        float sv[4][4];
#pragma unroll
        for (int ct = 0; ct < 4; ++ct) {
            int jg = j0 + ct * 16 + col;
#pragma unroll
            for (int r = 0; r < 4; ++r) {
                float x = sanit(s[ct][r]) * SCALE_;
                sv[ct][r] = (jg > i_row + r) ? NEG_ : x;
            }
        }

        // online softmax (row lives in one quad's 16 lanes)
        float alpha[4];
#pragma unroll
        for (int r = 0; r < 4; ++r) {
            float mx = fmaxf(fmaxf(sv[0][r], sv[1][r]), fmaxf(sv[2][r], sv[3][r]));
#pragma unroll
            for (int off = 1; off < 16; off <<= 1)
                mx = fmaxf(mx, __shfl_xor(mx, off, 64));
            float mn = fmaxf(m_i[r], mx);
            alpha[r] = __expf(fminf(0.f, m_i[r] - mn));
            m_i[r]   = mn;
        }
#pragma unroll
        for (int r = 0; r < 4; ++r) {
            float sum = 0.f;
#pragma unroll
            for (int ct = 0; ct < 4; ++ct) {
                float pv = __expf(fminf(0.f, sv[ct][r] - m_i[r]));
                sv[ct][r] = pv;
                sum += pv;
            }
#pragma unroll
            for (int off = 1; off < 16; off <<= 1)
                sum += __shfl_xor(sum, off, 64);
            l_i[r] = l_i[r] * alpha[r] + sum;
        }
#pragma unroll
        for (int dt = 0; dt < 8; ++dt)
#pragma unroll
            for (int r = 0; r < 4; ++r) o[dt][r] *= alpha[r];

        // P: C-layout -> LDS (per-wave) -> A-layout
#pragma unroll
        for (int ct = 0; ct < 4; ++ct)
#pragma unroll
            for (int r = 0; r < 4; ++r)
                Ps[w][quad * 4 + r][ct * 16 + col] = f2bf(sv[ct][r]);
        __syncthreads();

        // O += P V
#pragma unroll
        for (int kt = 0; kt < 2; ++kt) {
            short8 pf = *(const short8*)&Ps[w][col][kt * 32 + quad * 8];
#pragma unroll
            for (int dt = 0; dt < 8; ++dt) {
                short8 vf;
#pragma unroll
                for (int jj = 0; jj < 8; ++jj)
                    vf[jj] = (short)Vs[kt * 32 + quad * 8 + jj][dt * 16 + col];
                o[dt] = __builtin_amdgcn_mfma_f32_16x16x32_bf16(pf, vf, o[dt], 0, 0, 0);
            }
        }
    }

    // epilogue: normalize + store bf16
#pragma unroll
    for (int r = 0; r < 4; ++r) {
        float inv = 1.0f / fmaxf(l_i[r], 1e-30f);
        ushort_t* op = obuf + (size_t)(bS + i_row + r) * HID_ + h * HD_;
#pragma unroll
        for (int dt = 0; dt < 8; ++dt)
            op[dt * 16 + col] = f2bf_s(o[dt][r] * inv);
    }
}

// ---------------------------------------------------------------------------
// All inputs fp32, output fp32. Internal bf16. Buffers:
//   d_out (67 MB fp32): [0,33.5MB) = Q bf16 scratch; [33.5,67) = O bf16
//   scratch; finally the whole 67 MB = fp32 result of GEMM2.
//   d_ws: [0,16.8MB) = K/V bf16; then O bf16 copied to [0,33.5MB).
// ws high-water = 33.5 MB.
// ---------------------------------------------------------------------------
extern "C" void kernel_launch(void* const* d_in, const int* in_sizes, int n_in,
                              void* d_out, int out_size, void* d_ws, size_t ws_size,
                              hipStream_t stream) {
    const float* X    = (const float*)d_in[0];   // [8192, 2048] fp32
    const float* Wqkv = (const float*)d_in[1];   // [2048, 3072] fp32
    const float* Wo   = (const float*)d_in[2];   // [2048, 2048] fp32

    ushort_t* qb  = (ushort_t*)d_out;                   // Q bf16, 33.5 MB
    ushort_t* obf = (ushort_t*)d_out + (size_t)NTOK * HID_; // O bf16, high half
    ushort_t* kvb = (ushort_t*)d_ws;                    // K/V bf16, 16.8 MB
    ushort_t* oa  = (ushort_t*)d_ws;                    // O bf16 (after copy)

    // 1) QKV projection: fp32 in -> bf16 Q (d_out low) + bf16 K/V (ws)
    gemm_k<1, 1><<<dim3(QKV_N / 128, NTOK / 128), 256, 0, stream>>>(
        X, Wqkv, qb, kvb, NTOK, QKV_N, HID_);
    // 2) RoPE on Q and K
    rope_kernel<<<(NTOK * 20 * 64) / 256, 256, 0, stream>>>(qb, kvb);
    // 3) causal GQA flash attention: O bf16 -> d_out high half
    flash_kernel<<<dim3(S_ / 64, NH_, B_), 256, 0, stream>>>(qb, kvb, obf);
    // 4) move O into ws (K/V dead) so GEMM2 can safely write all of d_out
    hipMemcpyAsync(oa, obf, (size_t)NTOK * HID_ * sizeof(ushort_t),
                   hipMemcpyDeviceToDevice, stream);
    // 5) output projection: bf16 A, fp32 W, fp32 C -> d_out
    gemm_k<0, 0><<<dim3(HID_ / 128, NTOK / 128), 256, 0, stream>>>(
        oa, Wo, d_out, nullptr, NTOK, HID_, HID_);
}

// Round 5
// 1116.558 us; speedup vs baseline: 1.1565x; 1.1565x over previous
//
#include <hip/hip_runtime.h>

#define B_ 4
#define S_ 2048
#define HID_ 2048
#define NH_ 16
#define NKV_ 4
#define HD_ 128
#define NTOK (B_ * S_)                 // 8192
#define QKV_N 3072                     // (NH + 2*NKV) * HD
#define KO_N 512                       // K-only row length (4 kv heads * 128)
#define SCALE_ 0.08838834764831845f    // 128^-0.5
#define NEG_ -30000.0f

typedef __attribute__((ext_vector_type(8))) short short8;
typedef __attribute__((ext_vector_type(4))) short short4v;
typedef __attribute__((ext_vector_type(4))) float f32x4;
typedef unsigned short ushort_t;
typedef unsigned int uint32;

__device__ __forceinline__ float sanit(float x) {
    if (!(x == x)) x = 0.0f;
    return fminf(fmaxf(x, -65504.0f), 65504.0f);
}
__device__ __forceinline__ ushort_t f2bf(float f) {
    union { float f; uint32 u; } c; c.f = f;
    uint32 u = c.u;
    u += 0x7fffu + ((u >> 16) & 1u);          // round-to-nearest-even
    return (ushort_t)(u >> 16);
}
__device__ __forceinline__ ushort_t f2bf_s(float f) { return f2bf(sanit(f)); }
__device__ __forceinline__ float bf2f(ushort_t h) {
    union { float f; uint32 u; } c; c.u = ((uint32)h) << 16;
    return c.f;
}

// ---------------------------------------------------------------------------
// GEMM: C = A[M,K] @ B[K,N]. B fp32 weights. A fp32 (AF32=1) or bf16 (AF32=0).
// bf16 MFMA, fp32 acc. 128x128 tile, 4 waves of 64x64, BK=32.
// SPLIT=1 (QKV): cols <2048 -> Q rows [8192][2048] bf16 (C0);
//                2048..2559  -> K rows [8192][512] bf16 (C1);
//                2560..3071  -> V TRANSPOSED [512][8192] bf16 (C2):
//                               C2[vcol*8192 + token], vcol = kvh*128 + d.
// SPLIT=0: fp32 epilogue into C0 (ld N).
// ---------------------------------------------------------------------------
template <int SPLIT, int AF32>
__global__ __launch_bounds__(256, 2) void gemm_k(
    const void* __restrict__ Ap, const float* __restrict__ Bm,
    void* __restrict__ C0, ushort_t* __restrict__ C1, ushort_t* __restrict__ C2,
    int M, int N, int K) {
    __shared__ __align__(16) ushort_t As[128][40];
    __shared__ __align__(16) ushort_t Bs[128][40]; // transposed: Bs[n][k]

    const int tid  = threadIdx.x;
    const int lane = tid & 63;
    const int w    = tid >> 6;
    const int wm   = (w >> 1) * 64;
    const int wn   = (w & 1) * 64;
    const int m0   = blockIdx.y * 128;
    const int n0   = blockIdx.x * 128;
    const int col  = lane & 15;
    const int quad = lane >> 4;

    f32x4 acc[4][4] = {};

    const int ar = tid >> 1;          // A stage row 0..127
    const int ak = (tid & 1) * 16;    // A stage k-offset {0,16}
    const int br = tid >> 3;          // B stage k-row 0..31
    const int bn = (tid & 7) * 16;    // B stage n-offset {0..112}

    for (int k0 = 0; k0 < K; k0 += 32) {
        __syncthreads();
        {
            ushort_t ua[16];
            if (AF32) {
                const float* ag = (const float*)Ap + (size_t)(m0 + ar) * K + k0 + ak;
                union { float4 v; float f[4]; } t;
#pragma unroll
                for (int q = 0; q < 4; ++q) {
                    t.v = *(const float4*)(ag + q * 4);
#pragma unroll
                    for (int e = 0; e < 4; ++e) ua[q * 4 + e] = f2bf(t.f[e]);
                }
            } else {
                const ushort_t* ag = (const ushort_t*)Ap + (size_t)(m0 + ar) * K + k0 + ak;
                union { float4 v; ushort_t u[8]; } t0, t1;
                t0.v = *(const float4*)ag;
                t1.v = *(const float4*)(ag + 8);
#pragma unroll
                for (int e = 0; e < 8; ++e) { ua[e] = t0.u[e]; ua[8 + e] = t1.u[e]; }
            }
            *(short8*)&As[ar][ak]     = *(short8*)&ua[0];
            *(short8*)&As[ar][ak + 8] = *(short8*)&ua[8];

            const float* bg = Bm + (size_t)(k0 + br) * N + n0 + bn;
            union { float4 v; float f[4]; } tb;
#pragma unroll
            for (int q = 0; q < 4; ++q) {
                tb.v = *(const float4*)(bg + q * 4);
#pragma unroll
                for (int e = 0; e < 4; ++e) Bs[bn + q * 4 + e][br] = f2bf(tb.f[e]);
            }
        }
        __syncthreads();

        short8 af[4], bfr[4];
#pragma unroll
        for (int mt = 0; mt < 4; ++mt)
            af[mt] = *(const short8*)&As[wm + mt * 16 + col][quad * 8];
#pragma unroll
        for (int nt = 0; nt < 4; ++nt)
            bfr[nt] = *(const short8*)&Bs[wn + nt * 16 + col][quad * 8];
#pragma unroll
        for (int mt = 0; mt < 4; ++mt)
#pragma unroll
            for (int nt = 0; nt < 4; ++nt)
                acc[mt][nt] = __builtin_amdgcn_mfma_f32_16x16x32_bf16(
                    af[mt], bfr[nt], acc[mt][nt], 0, 0, 0);
    }

    if (SPLIT) {
        if (n0 >= 2560) {
            // V -> transposed global: 4 consecutive tokens packed per store
#pragma unroll
            for (int mt = 0; mt < 4; ++mt)
#pragma unroll
                for (int nt = 0; nt < 4; ++nt) {
                    int cc   = n0 + wn + nt * 16 + col - 2560;  // 0..511
                    int row0 = m0 + wm + mt * 16 + quad * 4;
                    short4v p;
#pragma unroll
                    for (int r = 0; r < 4; ++r) p[r] = (short)f2bf_s(acc[mt][nt][r]);
                    *(short4v*)&C2[(size_t)cc * NTOK + row0] = p;
                }
        } else {
            ushort_t* dst;
            int ldc, coff;
            if (n0 >= 2048) { dst = C1; ldc = KO_N; coff = 2048; }
            else            { dst = (ushort_t*)C0; ldc = HID_; coff = 0; }
#pragma unroll
            for (int mt = 0; mt < 4; ++mt)
#pragma unroll
                for (int nt = 0; nt < 4; ++nt)
#pragma unroll
                    for (int r = 0; r < 4; ++r) {
                        int row = m0 + wm + mt * 16 + quad * 4 + r;
                        int cc  = n0 + wn + nt * 16 + col - coff;
                        dst[(size_t)row * ldc + cc] = f2bf_s(acc[mt][nt][r]);
                    }
        }
    } else {
        float* dst = (float*)C0;
#pragma unroll
        for (int mt = 0; mt < 4; ++mt)
#pragma unroll
            for (int nt = 0; nt < 4; ++nt)
#pragma unroll
                for (int r = 0; r < 4; ++r) {
                    int row = m0 + wm + mt * 16 + quad * 4 + r;
                    int cc  = n0 + wn + nt * 16 + col;
                    dst[(size_t)row * N + cc] = sanit(acc[mt][nt][r]);
                }
    }
}

// ---------------------------------------------------------------------------
// RoPE in-place. Q in qbuf [8192][2048]; K in kb [8192][512].
// V (transposed) needs no RoPE. One thread per (tok, head, d<64).
// ---------------------------------------------------------------------------
__global__ void rope_kernel(ushort_t* __restrict__ qbuf,
                            ushort_t* __restrict__ kb) {
    int p = blockIdx.x * blockDim.x + threadIdx.x;
    const int total = NTOK * 20 * 64;
    if (p >= total) return;
    int d    = p & 63;
    int rest = p >> 6;
    int head = rest % 20;            // 0..15 Q, 16..19 K
    int tok  = rest / 20;
    int s    = tok & (S_ - 1);

    ushort_t* base;
    if (head < 16) base = qbuf + (size_t)tok * HID_ + head * HD_ + d;
    else           base = kb   + (size_t)tok * KO_N + (head - 16) * HD_ + d;

    float x1 = bf2f(base[0]);
    float x2 = bf2f(base[64]);

    float inv_freq = powf(10000.0f, -(float)d * (1.0f / 64.0f));
    float ang = (float)s * inv_freq;
    float sn, cs;
    sincosf(ang, &sn, &cs);

    base[0]  = f2bf_s(x1 * cs - x2 * sn);
    base[64] = f2bf_s(x2 * cs + x1 * sn);
}

// ---------------------------------------------------------------------------
// Flash attention, causal, GQA. 4 waves, BQ=64 (16 Q rows/wave), BK=64.
// K from kb [8192][512] (rows); V from vtg [512][8192] (d-major, transposed)
// -> LDS Vt[d][j] so PV B-fragments are contiguous ds_read_b128.
// Blocks launched heavy-first (reversed q0) to cut the causal tail.
// ---------------------------------------------------------------------------
__global__ __launch_bounds__(256, 2) void flash_kernel(
    const ushort_t* __restrict__ qbuf, const ushort_t* __restrict__ kb,
    const ushort_t* __restrict__ vtg, ushort_t* __restrict__ obuf) {
    __shared__ __align__(16) ushort_t Ks[64][136];  // [j][d], +8 pad
    __shared__ __align__(16) ushort_t Vt[128][72];  // [d][j], +8 pad
    __shared__ __align__(16) ushort_t Ps[4][16][72];

    const int tid  = threadIdx.x;
    const int lane = tid & 63;
    const int w    = tid >> 6;
    const int col  = lane & 15;
    const int quad = lane >> 4;
    const int q0   = (S_ / 64 - 1 - blockIdx.x) * 64;   // heavy blocks first
    const int h    = blockIdx.y;
    const int b    = blockIdx.z;
    const int kvh  = h >> 2;
    const int bS   = b * S_;

    short8 qf[4];
    {
        const ushort_t* qp = qbuf + (size_t)(bS + q0 + w * 16 + col) * HID_
                             + h * HD_ + quad * 8;
#pragma unroll
        for (int kt = 0; kt < 4; ++kt) qf[kt] = *(const short8*)(qp + kt * 32);
    }

    float m_i[4], l_i[4];
#pragma unroll
    for (int r = 0; r < 4; ++r) { m_i[r] = NEG_; l_i[r] = 0.f; }
    f32x4 o[8] = {};

    const int i_row  = q0 + w * 16 + quad * 4;   // + r
    const int ntiles = q0 / 64 + 1;

    const int jr   = tid >> 2;        // K stage row 0..63
    const int doff = (tid & 3) * 32;  // K stage d-offset
    const int vd   = tid >> 1;        // V stage d-row 0..127
    const int vjh  = (tid & 1) * 32;  // V stage j-offset {0,32}

    for (int t = 0; t < ntiles; ++t) {
        const int j0 = t * 64;
        __syncthreads();
        {
            const ushort_t* kg = kb + (size_t)(bS + j0 + jr) * KO_N
                                 + kvh * HD_ + doff;
            const ushort_t* vg = vtg + (size_t)(kvh * HD_ + vd) * NTOK
                                 + bS + j0 + vjh;
#pragma unroll
            for (int i = 0; i < 4; ++i) {
                *(float4*)&Ks[jr][doff + i * 8] = *(const float4*)(kg + i * 8);
                *(float4*)&Vt[vd][vjh + i * 8]  = *(const float4*)(vg + i * 8);
            }
        }
        __syncthreads();

        // S = Q K^T
        f32x4 s[4] = {};
#pragma unroll
        for (int ct = 0; ct < 4; ++ct)
#pragma unroll
            for (int kt = 0; kt < 4; ++kt) {
                short8 kf = *(const short8*)&Ks[ct * 16 + col][kt * 32 + quad * 8];
                s[ct] = __builtin_amdgcn_mfma_f32_16x16x32_bf16(qf[kt], kf, s[ct], 0, 0, 0);
            }

        // scale + causal mask
        float sv[4][4];
#pragma unroll
        for (int ct = 0; ct < 4; ++ct) {
            int jg = j0 + ct * 16 + col;
#pragma unroll
            for (int r = 0; r < 4; ++r) {
                float x = sanit(s[ct][r]) * SCALE_;
                sv[ct][r] = (jg > i_row + r) ? NEG_ : x;
            }
        }

        // online softmax (row lives in one quad's 16 lanes)
        float alpha[4];
#pragma unroll
        for (int r = 0; r < 4; ++r) {
            float mx = fmaxf(fmaxf(sv[0][r], sv[1][r]), fmaxf(sv[2][r], sv[3][r]));
#pragma unroll
            for (int off = 1; off < 16; off <<= 1)
                mx = fmaxf(mx, __shfl_xor(mx, off, 64));
            float mn = fmaxf(m_i[r], mx);
            alpha[r] = __expf(fminf(0.f, m_i[r] - mn));
            m_i[r]   = mn;
        }
#pragma unroll
        for (int r = 0; r < 4; ++r) {
            float sum = 0.f;
#pragma unroll
            for (int ct = 0; ct < 4; ++ct) {
                float pv = __expf(fminf(0.f, sv[ct][r] - m_i[r]));
                sv[ct][r] = pv;
                sum += pv;
            }
#pragma unroll
            for (int off = 1; off < 16; off <<= 1)
                sum += __shfl_xor(sum, off, 64);
            l_i[r] = l_i[r] * alpha[r] + sum;
        }
#pragma unroll
        for (int dt = 0; dt < 8; ++dt)
#pragma unroll
            for (int r = 0; r < 4; ++r) o[dt][r] *= alpha[r];

        // P: C-layout -> LDS (per-wave) -> A-layout
#pragma unroll
        for (int ct = 0; ct < 4; ++ct)
#pragma unroll
            for (int r = 0; r < 4; ++r)
                Ps[w][quad * 4 + r][ct * 16 + col] = f2bf(sv[ct][r]);
        __syncthreads();

        // O += P V  (vf now one contiguous ds_read_b128 from Vt)
#pragma unroll
        for (int kt = 0; kt < 2; ++kt) {
            short8 pf = *(const short8*)&Ps[w][col][kt * 32 + quad * 8];
#pragma unroll
            for (int dt = 0; dt < 8; ++dt) {
                short8 vf = *(const short8*)&Vt[dt * 16 + col][kt * 32 + quad * 8];
                o[dt] = __builtin_amdgcn_mfma_f32_16x16x32_bf16(pf, vf, o[dt], 0, 0, 0);
            }
        }
    }

    // epilogue: normalize + store bf16
#pragma unroll
    for (int r = 0; r < 4; ++r) {
        float inv = 1.0f / fmaxf(l_i[r], 1e-30f);
        ushort_t* op = obuf + (size_t)(bS + i_row + r) * HID_ + h * HD_;
#pragma unroll
        for (int dt = 0; dt < 8; ++dt)
            op[dt * 16 + col] = f2bf_s(o[dt][r] * inv);
    }
}

// ---------------------------------------------------------------------------
// fp32 in, fp32 out, bf16 internal. Buffers:
//   d_out: [0,33.5MB) Q bf16; [33.5,67) O bf16; finally full fp32 result.
//   ws: [0,8.4) K bf16 rows; [8.4,16.8) V bf16 transposed; then O bf16
//       copied to [0,33.5) for GEMM2. ws high-water = 33.5 MB.
// ---------------------------------------------------------------------------
extern "C" void kernel_launch(void* const* d_in, const int* in_sizes, int n_in,
                              void* d_out, int out_size, void* d_ws, size_t ws_size,
                              hipStream_t stream) {
    const float* X    = (const float*)d_in[0];   // [8192, 2048] fp32
    const float* Wqkv = (const float*)d_in[1];   // [2048, 3072] fp32
    const float* Wo   = (const float*)d_in[2];   // [2048, 2048] fp32

    ushort_t* qb  = (ushort_t*)d_out;                        // Q bf16
    ushort_t* obf = (ushort_t*)d_out + (size_t)NTOK * HID_;  // O bf16
    ushort_t* kb  = (ushort_t*)d_ws;                         // K rows
    ushort_t* vtg = kb + (size_t)NTOK * KO_N;                // V transposed
    ushort_t* oa  = (ushort_t*)d_ws;                         // O (after copy)

    // 1) QKV projection: Q -> d_out low, K rows -> ws, V transposed -> ws
    gemm_k<1, 1><<<dim3(QKV_N / 128, NTOK / 128), 256, 0, stream>>>(
        X, Wqkv, qb, kb, vtg, NTOK, QKV_N, HID_);
    // 2) RoPE on Q and K
    rope_kernel<<<(NTOK * 20 * 64) / 256, 256, 0, stream>>>(qb, kb);
    // 3) causal GQA flash attention: O bf16 -> d_out high half
    flash_kernel<<<dim3(S_ / 64, NH_, B_), 256, 0, stream>>>(qb, kb, vtg, obf);
    // 4) move O into ws (K/V dead) so GEMM2 can write all of d_out
    hipMemcpyAsync(oa, obf, (size_t)NTOK * HID_ * sizeof(ushort_t),
                   hipMemcpyDeviceToDevice, stream);
    // 5) output projection: bf16 A, fp32 W, fp32 C -> d_out
    gemm_k<0, 0><<<dim3(HID_ / 128, NTOK / 128), 256, 0, stream>>>(
        oa, Wo, d_out, nullptr, nullptr, NTOK, HID_, HID_);
}